// Round 11
// baseline (343.746 us; speedup 1.0000x reference)
//
#include <hip/hip_runtime.h>
#include <hip/hip_bf16.h>

typedef int i32x4 __attribute__((ext_vector_type(4)));
typedef unsigned int u32;
typedef unsigned long long u64;
typedef long long ll;

// async 16B global->LDS copy. LDS dest = wave-uniform base + lane*16.
__device__ __forceinline__ void load_lds16(const void* g, void* l) {
  __builtin_amdgcn_global_load_lds(
      (const __attribute__((address_space(1))) u32*)g,
      (__attribute__((address_space(3))) u32*)l, 16, 0, 0);
}

// ---------------------------------------------------------------------------
// prep_all: weight packing via LDS transpose (coalesced reads) + totw sums.
// (unchanged)
// ---------------------------------------------------------------------------
__global__ __launch_bounds__(256) void prep_all(
    const float* __restrict__ w0, const float* __restrict__ w1,
    const float* __restrict__ w2, const float* __restrict__ w3,
    signed char* __restrict__ w0q, signed char* __restrict__ w1p,
    signed char* __restrict__ w2p, signed char* __restrict__ w3p,
    signed char* __restrict__ zbuf,
    int* __restrict__ totw0, int* __restrict__ totw1,
    int* __restrict__ totw2, int* __restrict__ totw3)
{
  __shared__ signed char ldsw[8 * 4800];   // 38400 B
  const int blk = blockIdx.x;
  const int tid = threadIdx.x;

  if (blk < 88) {
    const float* wsrc; signed char* wdst; int* tot; int MF, sub;
    if (blk < 24)      { wsrc = w1; wdst = w1p; tot = totw1; MF = 12; sub = blk; }
    else if (blk < 48) { wsrc = w2; wdst = w2p; tot = totw2; MF = 12; sub = blk - 24; }
    else               { wsrc = w3; wdst = w3p; tot = totw3; MF = 20; sub = blk - 48; }
    const int mf = sub >> 1, half = sub & 1, colbase = half * 8;
    const int ocb = mf * 16 + colbase;
    // ---- phase A: coalesced read + quantize + per-oc sums ----
    for (int o = 0; o < 8; o++) {
      const float* src = wsrc + (size_t)(ocb + o) * 4800;
      int s = 0;
      for (int j = tid; j < 4800; j += 256) {
        int v = (int)rintf(src[j]);
        ldsw[o * 4800 + j] = (signed char)v;
        s += v;
      }
      atomicAdd(&tot[ocb + o], s);
    }
    __syncthreads();
    // ---- phase B: packed u32 writes (coalesced) ----
    for (int u = tid; u < 9600; u += 256) {
      int eu = u & 3, colL = (u >> 2) & 7, q = (u >> 5) & 3, t = u >> 7;
      int tap = t / 3, ch = t - 3 * tap;
      int ci0 = ch * 64 + q * 16 + eu * 4;
      const signed char* sp = ldsw + colL * 4800 + tap;
      u32 wv = 0;
      #pragma unroll
      for (int bb = 0; bb < 4; bb++)
        wv |= ((u32)(unsigned char)sp[(ci0 + bb) * 25]) << (8 * bb);
      *(u32*)(wdst + ((size_t)t * MF + mf) * 1024 +
              (q * 16 + colbase + colL) * 16 + eu * 4) = wv;
    }
  } else {
    // ---- blk 88: zbuf + w0q custom pack + w0 sums ----
    if (tid < 128) ((u64*)zbuf)[tid] = 0x8080808080808080ULL;
    for (int i = tid; i < 24576; i += 256) {
      int e = i & 15, colA = (i >> 4) & 15, q = (i >> 8) & 3, t = i >> 10;
      int mf = t % 12, ch = t / 12;
      signed char v = 0;
      if (e < 15 && (ch == 0 || q == 0)) {
        int ky = (ch == 0) ? q : 4;
        int ci = e / 5, kx = e - ci * 5;
        v = (signed char)(int)rintf(
            w0[((mf * 16 + colA) * 3 + ci) * 25 + ky * 5 + kx]);
      }
      w0q[i] = v;
    }
    for (int oc = tid; oc < 192; oc += 256) {
      const float* p = w0 + (size_t)oc * 75;
      int s = 0;
      #pragma unroll 5
      for (int j = 0; j < 75; j++) s += (int)rintf(p[j]);
      totw0[oc] = s;
    }
  }
}

// ---------------------------------------------------------------------------
// conv0F: fused layer-0 (unchanged).
// ---------------------------------------------------------------------------
__global__ __launch_bounds__(192, 3) void conv0F(
    const float* __restrict__ x, const signed char* __restrict__ wq,
    const float* __restrict__ bias, const float* __restrict__ mulv,
    const int* __restrict__ totw,
    const int* __restrict__ reluP, const int* __restrict__ mdP,
    unsigned char* __restrict__ outA)
{
  __shared__ signed char ilds[3][5][132];

  const int tid = threadIdx.x;
  const int lane = tid & 63;
  const int col = lane & 15;
  const int quad = lane >> 4;
  const int w = tid >> 6;
  const int blk = blockIdx.x;
  const int oxblk = blk & 3;
  const int oy = (blk >> 2) & 255;
  const int b = blk >> 10;
  const int oxbase = oxblk * 64;

  i32x4 afr[2][4];
  #pragma unroll
  for (int ch = 0; ch < 2; ch++)
    #pragma unroll
    for (int i = 0; i < 4; i++)
      afr[ch][i] = *(const i32x4*)(wq + ch * 12288 + (w * 4 + i) * 1024 + lane * 16);

  const float* xb = x + (size_t)b * 3 * 512 * 512;
  for (int i = tid; i < 990; i += 192) {
    int j = i % 66; int t = i / 66; int r = t % 5; int ci = t / 5;
    int iy = 2 * oy - 2 + r;
    int ix = 2 * oxbase - 2 + 2 * j;
    int v0 = -128, v1 = -128;
    if ((unsigned)iy < 512u) {
      const float* row = xb + ((size_t)ci * 512 + iy) * 512;
      if ((unsigned)ix < 512u) {
        float xv = rintf(row[ix] * 256.0f);
        v0 = (int)fminf(fmaxf(xv, 0.0f), 255.0f) - 128;
      }
      if ((unsigned)(ix + 1) < 512u) {
        float xv = rintf(row[ix + 1] * 256.0f);
        v1 = (int)fminf(fmaxf(xv, 0.0f), 255.0f) - 128;
      }
    }
    *(unsigned short*)&ilds[ci][r][2 * j] =
        (unsigned short)((v0 & 0xFF) | ((v1 & 0xFF) << 8));
  }
  __syncthreads();

  i32x4 acc[4][4];
  #pragma unroll
  for (int fm = 0; fm < 4; fm++)
    #pragma unroll
    for (int fn = 0; fn < 4; fn++) acc[fm][fn] = (i32x4){0, 0, 0, 0};

  #pragma unroll
  for (int ch = 0; ch < 2; ch++) {
    const int row = (ch == 0) ? quad : 4;
    i32x4 bfr[4];
    #pragma unroll
    for (int fn = 0; fn < 4; fn++) {
      const int xb2 = 2 * (fn * 16 + col);
      const int o8 = (xb2 & 3) * 8;
      const int ab = xb2 & ~3;
      u64 w0_, w1_, w2_;
      {
        const u32* p0 = (const u32*)&ilds[0][row][ab];
        const u32* p1 = (const u32*)&ilds[1][row][ab];
        const u32* p2 = (const u32*)&ilds[2][row][ab];
        w0_ = (u64)p0[0] | ((u64)p0[1] << 32);
        w1_ = (u64)p1[0] | ((u64)p1[1] << 32);
        w2_ = (u64)p2[0] | ((u64)p2[1] << 32);
      }
      u32 a0 = (u32)(w0_ >> o8);
      u32 a1 = ((u32)(w0_ >> (o8 + 32)) & 0xFFu) | (((u32)(w1_ >> o8)) << 8);
      u32 a2 = ((u32)(w1_ >> (o8 + 24)) & 0xFFFFu) | (((u32)(w2_ >> o8)) << 16);
      u32 a3 = (u32)(w2_ >> (o8 + 16));
      bfr[fn] = (i32x4){(int)a0, (int)a1, (int)a2, (int)a3};
    }
    #pragma unroll
    for (int fm = 0; fm < 4; fm++)
      #pragma unroll
      for (int fn = 0; fn < 4; fn++)
        acc[fm][fn] = __builtin_amdgcn_mfma_i32_16x16x64_i8(
            afr[ch][fm], bfr[fn], acc[fm][fn], 0, 0, 0);
  }

  const size_t pix0 = ((size_t)(b * 256 + oy)) * 256 + oxbase;
  const int rl = reluP[0];
  const int sh = mdP[0];
  const ll clpv_ll = llrint(255.0 / (double)rl * 16777216.0);
  const int clpv = clpv_ll > 0x7FFFFFFFLL ? 0x7FFFFFFF : (int)clpv_ll;
  const int sclv = (int)((rl + 4) >> 3);
  const int rnd = 1 << (sh - 1);
  #pragma unroll
  for (int fm = 0; fm < 4; fm++) {
    const int oc0 = w * 64 + fm * 16 + quad * 4;
    int bim[4], mu32[4];
    #pragma unroll
    for (int r = 0; r < 4; r++) {
      int bi = (int)llrintf(bias[oc0 + r] * 256.0f) + 128 * totw[oc0 + r];
      mu32[r] = (int)llrintf(mulv[oc0 + r]);
      bim[r] = bi * mu32[r];
    }
    #pragma unroll
    for (int fn = 0; fn < 4; fn++) {
      const size_t pix = pix0 + fn * 16 + col;
      u32 wd = 0;
      #pragma unroll
      for (int r = 0; r < 4; r++) {
        int vi = acc[fm][fn][r] * mu32[r] + bim[r];
        int y = (vi + rnd) >> sh;
        y = y < 0 ? 0 : (y > clpv ? clpv : y);
        y = (y * sclv + (1 << 20)) >> 21;
        wd |= (((u32)y ^ 0x80u) & 0xFFu) << (8 * r);
      }
      *(u32*)(outA + pix * 192 + oc0) = wd;
    }
  }
}

// ---------------------------------------------------------------------------
// Layers 1-3: all-compute FIFO pipeline + 2-UNIT SUPER-STEPS.
// One barrier covers TWO K-units: per super each wave does 2*NB ds_read +
// 2*FM*NB MFMA (L1: 16 reads, 48 MFMA) — halves barrier count (75 -> 40)
// and amortizes per-step fixed costs (barrier skew, lgkm batch, issue).
// Ring: 6 unit-buffers (L1/L2: 48 KB -> 2 blocks/CU at 96 KB). FIFO
// invariant (in-order vmcnt retirement, m135): comp(u) auto-waits A(u),
// and A(u) is always issued AFTER stage(u) (stage(u) at super s-2, A(u) at
// super s-1) => stage(u) landed. WAR: slot u%6 was last read at unit u-6,
// two barriers earlier. A-banks: 4 named arrays (a0..a3), pair-of-supers
// unrolled loop — all indices compile-time (no scratch).
// ---------------------------------------------------------------------------
template <int COUT, int HIN, int WIN, int HOUT, int WOUT, int WV,
          int KSPLIT, bool DIRECT, int NH>
__global__ __launch_bounds__(WV * 64, 2) void convS(
    const signed char* __restrict__ act, const signed char* __restrict__ wp,
    const float* __restrict__ bias, const float* __restrict__ mulv,
    const int* __restrict__ totw,
    const int* __restrict__ reluP, const int* __restrict__ mdP,
    const signed char* __restrict__ zbuf,
    unsigned char* __restrict__ outA, int* __restrict__ outP)
{
  constexpr int CIN = 192;
  constexpr int PASSES = 4;
  constexpr int MF = COUT / 16;
  constexpr int OCW = COUT / WV;          // oc per wave (48 or 64)
  constexpr int FM = OCW / 16;            // MFMA row-tiles per wave (3 or 4)
  constexpr int SAe = MF * 1024;          // A bytes per (tap,ch) unit
  constexpr int TX = WOUT / (16 * NH);
  constexpr int TYB = HOUT / 4;
  constexpr int TPP = 25 / KSPLIT;
  constexpr int NSTEP = TPP * 3;          // 75 or 15
  constexpr int NB = PASSES * NH;         // convoys / B-frags per unit
  constexpr int BUFB = NB * 1024;
  constexpr int RING = 6;
  constexpr int SMAX = (NB + WV - 1) / WV;
  constexpr int NSUP2 = NSTEP / 4;        // pairs of 2-unit supers
  constexpr int VC = 2 * (NB >= WV ? NB / WV : 1);
  constexpr int PSZ = 4 * HOUT * WOUT * COUT;
  static_assert(WV * OCW == COUT, "M covers COUT");
  static_assert(NSTEP % 4 == 3, "tail structure assumes NSTEP = 4k+3");

  __shared__ __align__(16) char smem[RING * BUFB];

  const int tid = threadIdx.x;
  const int lane = tid & 63;
  const int col = lane & 15;
  const int quad = lane >> 4;
  const int w = tid >> 6;
  const int part = blockIdx.y;

  int bx = blockIdx.x;
  const int tx = bx % TX; bx /= TX;
  const int ty = bx % TYB;
  const int b = bx / TYB;
  const int ox0 = tx * 16 * NH;
  const int oy0 = ty * 4;
  const int tap0 = part * TPP;

  // ---- staging share: convoys j = w + k*WV (k < SMAX, j < NB) ----
  const signed char* bp[SMAX];
  int mjx[SMAX], mjy[SMAX];
  #pragma unroll
  for (int k = 0; k < SMAX; k++) {
    const int j = w + k * WV;
    if (j < NB) {
      const int p = j / NH, h = j % NH;
      const int oxv = ox0 + h * 16 + col;
      const int oyv = oy0 + p;
      bp[k] = act + ((size_t)b * HIN * WIN + (size_t)(2 * oyv) * WIN + 2 * oxv) * CIN
              + quad * 16;
      int mx = 0, my = 0;
      #pragma unroll
      for (int kk = 0; kk < 5; kk++) {
        if ((unsigned)(2 * oxv + kk - 2) < (unsigned)WIN) mx |= 1 << kk;
        if ((unsigned)(2 * oyv + kk - 2) < (unsigned)HIN) my |= 1 << kk;
      }
      mjx[k] = mx; mjy[k] = my;
    }
  }
  int kyS = tap0 / 5, kxS = tap0 - 5 * kyS, chS = 0;
  int ssl = 0;                             // ring slot of next stage
  auto stage = [&]() {
    const int offB = ((kyS - 2) * WIN + (kxS - 2)) * CIN + chS * 64;
    #pragma unroll
    for (int k = 0; k < SMAX; k++) {
      const int j = w + k * WV;
      if (j < NB) {
        bool v = ((mjx[k] >> kxS) & 1) && ((mjy[k] >> kyS) & 1);
        const signed char* g = v ? (bp[k] + offB) : (zbuf + quad * 16);
        load_lds16(g, smem + ssl * BUFB + j * 1024);
      }
    }
    chS++;
    if (chS == 3) { chS = 0; kxS++; if (kxS == 5) { kxS = 0; kyS++; } }
    ssl = (ssl + 1 == RING) ? 0 : ssl + 1;
  };

  // ---- accumulators / A banks ----
  i32x4 acc[FM][NB];
  #pragma unroll
  for (int fm = 0; fm < FM; fm++)
    #pragma unroll
    for (int j = 0; j < NB; j++) acc[fm][j] = (i32x4){0, 0, 0, 0};

  auto loadA = [&](int u, i32x4 (&dst)[FM]) {
    const signed char* p = wp + (size_t)(tap0 * 3 + u) * SAe + w * FM * 1024 + lane * 16;
    #pragma unroll
    for (int i = 0; i < FM; i++) dst[i] = *(const i32x4*)(p + i * 1024);
  };

  int rb = 0;                              // ring slot of next comp
  auto cslot = [&]() { int t = rb; rb = (rb + 1 == RING) ? 0 : rb + 1; return t; };
  auto comp = [&](int slot, i32x4 (&a)[FM]) {
    const char* pB = smem + slot * BUFB + lane * 16;
    i32x4 bfr[NB];
    #pragma unroll
    for (int i = 0; i < NB; i++)
      bfr[i] = *(const i32x4*)(pB + i * 1024);
    #pragma unroll
    for (int fm = 0; fm < FM; fm++)
      #pragma unroll
      for (int j = 0; j < NB; j++)
        acc[fm][j] = __builtin_amdgcn_mfma_i32_16x16x64_i8(
            a[fm], bfr[j], acc[fm][j], 0, 0, 0);
  };

  i32x4 a0[FM], a1[FM], a2[FM], a3[FM];
  // ---- prologue: A(0),A(1); stage units 0..3; wait A+stage(0,1) ----
  loadA(0, a0); loadA(1, a1);
  stage(); stage(); stage(); stage();
  if constexpr (VC == 4) asm volatile("s_waitcnt vmcnt(4)" ::: "memory");
  else                   asm volatile("s_waitcnt vmcnt(2)" ::: "memory");
  asm volatile("s_barrier" ::: "memory");

  #pragma unroll 1
  for (int i2 = 0; i2 < NSUP2; ++i2) {
    const int u0 = 4 * i2;
    // super A: units u0, u0+1
    loadA(u0 + 2, a2); loadA(u0 + 3, a3);
    stage(); stage();                      // units u0+4, u0+5 (always < NSTEP)
    comp(cslot(), a0); comp(cslot(), a1);
    asm volatile("s_barrier" ::: "memory");
    // super B: units u0+2, u0+3
    loadA(u0 + 4, a0); loadA(u0 + 5, a1);
    stage();                               // unit u0+6 (<= NSTEP-1)
    if (u0 + 7 < NSTEP) stage();           // unit u0+7
    comp(cslot(), a2); comp(cslot(), a3);
    asm volatile("s_barrier" ::: "memory");
  }
  // ---- tail: units NSTEP-3, NSTEP-2, NSTEP-1 (a0,a1 already loaded) ----
  loadA(NSTEP - 1, a2);
  comp(cslot(), a0); comp(cslot(), a1);
  asm volatile("s_barrier" ::: "memory");
  comp(cslot(), a2);

  // ---- epilogue ----
  if constexpr (DIRECT) {
    const int rl = reluP[0];
    const int sh = mdP[0] - 8;
    const ll clpv = llrint(255.0 / (double)rl * 16777216.0);
    const ll sclv = (ll)((rl + 4) >> 3);
    #pragma unroll
    for (int fm = 0; fm < FM; fm++) {
      const int oc0 = w * OCW + fm * 16 + quad * 4;
      ll bi[4], mu[4];
      #pragma unroll
      for (int r = 0; r < 4; r++) {
        bi[r] = llrintf(bias[oc0 + r]) + 128LL * totw[oc0 + r];
        mu[r] = llrintf(mulv[oc0 + r]);
      }
      #pragma unroll
      for (int j = 0; j < NB; j++) {
        const int p = j / NH, h = j % NH;
        const int oyv = oy0 + p;
        const int oxv = ox0 + h * 16 + col;
        u32 wd = 0;
        #pragma unroll
        for (int r = 0; r < 4; r++) {
          ll vi = ((ll)acc[fm][j][r] + bi[r]) * mu[r];
          ll y = (vi + (1LL << (sh - 1))) >> sh;
          y = y < 0 ? 0LL : (y > clpv ? clpv : y);
          y = (y * sclv + (1LL << 20)) >> 21;
          wd |= (((u32)y ^ 0x80u) & 0xFFu) << (8 * r);
        }
        *(u32*)(outA + ((size_t)((b * HOUT + oyv) * WOUT + oxv)) * COUT + oc0) = wd;
      }
    }
  } else {
    int* pout = outP + (size_t)part * PSZ;
    #pragma unroll
    for (int fm = 0; fm < FM; fm++) {
      const int oc0 = w * OCW + fm * 16 + quad * 4;
      #pragma unroll
      for (int j = 0; j < NB; j++) {
        const int p = j / NH, h = j % NH;
        const int oyv = oy0 + p;
        const int oxv = ox0 + h * 16 + col;
        *(i32x4*)(pout + ((size_t)((b * HOUT + oyv) * WOUT + oxv)) * COUT + oc0) =
            acc[fm][j];
      }
    }
  }
}

// ---------------------------------------------------------------------------
// reduce2: sum 5 L2 partials + integer epilogue -> act3 (i8, channels-last).
// ---------------------------------------------------------------------------
__global__ __launch_bounds__(256) void reduce2(
    const int* __restrict__ partP, const float* __restrict__ bias,
    const float* __restrict__ mulv, const int* __restrict__ totw,
    const int* __restrict__ reluP, const int* __restrict__ mdP,
    unsigned char* __restrict__ outA)
{
  const int gid = blockIdx.x * 256 + threadIdx.x;   // 786432
  const int PSZ4 = 4 * 64 * 64 * 192 / 4;
  const int4* pp = (const int4*)partP;
  int4 sv = pp[gid];
  #pragma unroll
  for (int p = 1; p < 5; p++) {
    int4 v = pp[(size_t)p * PSZ4 + gid];
    sv.x += v.x; sv.y += v.y; sv.z += v.z; sv.w += v.w;
  }
  int sa[4] = {sv.x, sv.y, sv.z, sv.w};
  const int oc0 = (gid * 4) % 192;
  const int rl = reluP[0];
  const int sh = mdP[0] - 8;
  const ll clpv = llrint(255.0 / (double)rl * 16777216.0);
  const ll sclv = (ll)((rl + 4) >> 3);
  u32 wd = 0;
  #pragma unroll
  for (int r = 0; r < 4; r++) {
    ll bi = llrintf(bias[oc0 + r]) + 128LL * totw[oc0 + r];
    ll mu = llrintf(mulv[oc0 + r]);
    ll vi = ((ll)sa[r] + bi) * mu;
    ll y = (vi + (1LL << (sh - 1))) >> sh;
    y = y < 0 ? 0LL : (y > clpv ? clpv : y);
    y = (y * sclv + (1LL << 20)) >> 21;
    wd |= (((u32)y ^ 0x80u) & 0xFFu) << (8 * r);
  }
  ((u32*)outA)[gid] = wd;
}

// ---------------------------------------------------------------------------
// reduce3: sum 5 L3 partials + final shift -> d_out f32 NCHW (coalesced write).
// ---------------------------------------------------------------------------
__global__ __launch_bounds__(256) void reduce3(
    const int* __restrict__ partP, const float* __restrict__ b3,
    const float* __restrict__ mul3, const int* __restrict__ totw3,
    const int* __restrict__ mdP, const int* __restrict__ gaP,
    float* __restrict__ outF)
{
  const int gid = blockIdx.x * 256 + threadIdx.x;   // 1310720
  int t = gid;
  const int ox = t & 31; t >>= 5;
  const int oy = t & 31; t >>= 5;
  const int oc = t % 320;
  const int b  = t / 320;
  const int PSZ = 4 * 32 * 32 * 320;
  const size_t src = ((size_t)((b * 32 + oy) * 32 + ox)) * 320 + oc;
  ll s = 0;
  #pragma unroll
  for (int p = 0; p < 5; p++) s += partP[(size_t)p * PSZ + src];
  const int sh = mdP[0] - gaP[0];
  const ll bi = llrintf(b3[oc]) + 128LL * totw3[oc];
  const ll mu = llrintf(mul3[oc]);
  const ll y = ((s + bi) * mu + (1LL << (sh - 1))) >> sh;
  outF[gid] = (float)y;
}

// ---------------------------------------------------------------------------
extern "C" void kernel_launch(void* const* d_in, const int* in_sizes, int n_in,
                              void* d_out, int out_size, void* d_ws, size_t ws_size,
                              hipStream_t stream)
{
  const float* x    = (const float*)d_in[0];
  const float* w0   = (const float*)d_in[1];
  const float* b0   = (const float*)d_in[2];
  const float* w1   = (const float*)d_in[3];
  const float* b1   = (const float*)d_in[4];
  const float* w2   = (const float*)d_in[5];
  const float* b2   = (const float*)d_in[6];
  const float* w3   = (const float*)d_in[7];
  const float* b3   = (const float*)d_in[8];
  const float* mul0 = (const float*)d_in[9];
  const float* mul1 = (const float*)d_in[10];
  const float* mul2 = (const float*)d_in[11];
  const float* mul3 = (const float*)d_in[12];
  const int* relu0  = (const int*)d_in[13];
  const int* relu1  = (const int*)d_in[14];
  const int* relu2  = (const int*)d_in[15];
  const int* md0    = (const int*)d_in[16];
  const int* md1    = (const int*)d_in[17];
  const int* md2    = (const int*)d_in[18];
  const int* md3    = (const int*)d_in[19];
  const int* ga     = (const int*)d_in[20];

  char* ws = (char*)d_ws;
  size_t off = 0;
  signed char* zbuf = (signed char*)(ws + off); off += 1024;
  signed char* w0q  = (signed char*)(ws + off); off += 24576;
  signed char* w1p  = (signed char*)(ws + off); off += 921600;
  signed char* w2p  = (signed char*)(ws + off); off += 921600;
  signed char* w3p  = (signed char*)(ws + off); off += 1536000;
  int*         totw1= (int*)        (ws + off); off += 192 * 4;
  int*         totw2= (int*)        (ws + off); off += 192 * 4;
  int*         totw3= (int*)        (ws + off); off += 320 * 4;
  int*         totw0= (int*)        (ws + off); off += 192 * 4;
  unsigned char* act1 = (unsigned char*)(ws + off); off += (size_t)4 * 256 * 256 * 192;
  unsigned char* act2 = (unsigned char*)(ws + off); off += (size_t)4 * 128 * 128 * 192;
  unsigned char* act3 = (unsigned char*)(ws + off); off += (size_t)4 * 64 * 64 * 192;
  int*         partl  = (int*)(ws + off); off += (size_t)5 * 4 * 64 * 64 * 192 * 4; // 62.9MB
  (void)ws_size; (void)in_sizes; (void)n_in; (void)out_size;

  hipMemsetAsync(totw1, 0, (192 + 192 + 320 + 192) * 4, stream);
  // weight packing (LDS transpose) + weight sums
  prep_all<<<89, 256, 0, stream>>>(w0, w1, w2, w3, w0q, w1p, w2p, w3p,
                                   zbuf, totw0, totw1, totw2, totw3);
  // L0 fused: quantize + in-register im2col + GEMM (M=192, N=262144, K=128)
  conv0F<<<4096, 192, 0, stream>>>(x, w0q, b0, mul0, totw0, relu0, md0, act1);
  // L1: 256x256 -> 128x128x192 ; 512 blocks x 4 waves ; N=128 ; 2-unit supers
  convS<192, 256, 256, 128, 128, 4, 1, true, 2><<<dim3(512, 1), 256, 0, stream>>>(
      (const signed char*)act1, w1p, b1, mul1, totw1, relu1, md1, zbuf, act2, nullptr);
  // L2: 128x128 -> 64x64x192 ; split-K 5 ; N=128 ; 2-unit supers
  convS<192, 128, 128, 64, 64, 4, 5, false, 2><<<dim3(128, 5), 256, 0, stream>>>(
      (const signed char*)act2, w2p, b2, mul2, totw2, relu2, md2, zbuf, nullptr, partl);
  reduce2<<<3072, 256, 0, stream>>>(partl, b2, mul2, totw2, relu2, md2, act3);
  // L3: 64x64 -> 32x32x320 ; split-K 5 ; 5 waves ; N=64 ; 2-unit supers
  convS<320, 64, 64, 32, 32, 5, 5, false, 1><<<dim3(64, 5), 320, 0, stream>>>(
      (const signed char*)act3, w3p, b3, mul3, totw3, nullptr, md3, zbuf, nullptr, partl);
  reduce3<<<5120, 256, 0, stream>>>(partl, b3, mul3, totw3, md3, ga, (float*)d_out);
}

// Round 12
// 338.250 us; speedup vs baseline: 1.0162x; 1.0162x over previous
//
#include <hip/hip_runtime.h>
#include <hip/hip_bf16.h>

typedef int i32x4 __attribute__((ext_vector_type(4)));
typedef unsigned int u32;
typedef unsigned long long u64;
typedef long long ll;

// async 16B global->LDS copy. LDS dest = wave-uniform base + lane*16.
__device__ __forceinline__ void load_lds16(const void* g, void* l) {
  __builtin_amdgcn_global_load_lds(
      (const __attribute__((address_space(1))) u32*)g,
      (__attribute__((address_space(3))) u32*)l, 16, 0, 0);
}

// ---------------------------------------------------------------------------
// prep_all: weight packing via LDS transpose (coalesced reads) + totw sums.
// (unchanged)
// ---------------------------------------------------------------------------
__global__ __launch_bounds__(256) void prep_all(
    const float* __restrict__ w0, const float* __restrict__ w1,
    const float* __restrict__ w2, const float* __restrict__ w3,
    signed char* __restrict__ w0q, signed char* __restrict__ w1p,
    signed char* __restrict__ w2p, signed char* __restrict__ w3p,
    signed char* __restrict__ zbuf,
    int* __restrict__ totw0, int* __restrict__ totw1,
    int* __restrict__ totw2, int* __restrict__ totw3)
{
  __shared__ signed char ldsw[8 * 4800];   // 38400 B
  const int blk = blockIdx.x;
  const int tid = threadIdx.x;

  if (blk < 88) {
    const float* wsrc; signed char* wdst; int* tot; int MF, sub;
    if (blk < 24)      { wsrc = w1; wdst = w1p; tot = totw1; MF = 12; sub = blk; }
    else if (blk < 48) { wsrc = w2; wdst = w2p; tot = totw2; MF = 12; sub = blk - 24; }
    else               { wsrc = w3; wdst = w3p; tot = totw3; MF = 20; sub = blk - 48; }
    const int mf = sub >> 1, half = sub & 1, colbase = half * 8;
    const int ocb = mf * 16 + colbase;
    // ---- phase A: coalesced read + quantize + per-oc sums ----
    for (int o = 0; o < 8; o++) {
      const float* src = wsrc + (size_t)(ocb + o) * 4800;
      int s = 0;
      for (int j = tid; j < 4800; j += 256) {
        int v = (int)rintf(src[j]);
        ldsw[o * 4800 + j] = (signed char)v;
        s += v;
      }
      atomicAdd(&tot[ocb + o], s);
    }
    __syncthreads();
    // ---- phase B: packed u32 writes (coalesced) ----
    for (int u = tid; u < 9600; u += 256) {
      int eu = u & 3, colL = (u >> 2) & 7, q = (u >> 5) & 3, t = u >> 7;
      int tap = t / 3, ch = t - 3 * tap;
      int ci0 = ch * 64 + q * 16 + eu * 4;
      const signed char* sp = ldsw + colL * 4800 + tap;
      u32 wv = 0;
      #pragma unroll
      for (int bb = 0; bb < 4; bb++)
        wv |= ((u32)(unsigned char)sp[(ci0 + bb) * 25]) << (8 * bb);
      *(u32*)(wdst + ((size_t)t * MF + mf) * 1024 +
              (q * 16 + colbase + colL) * 16 + eu * 4) = wv;
    }
  } else {
    // ---- blk 88: zbuf + w0q custom pack + w0 sums ----
    if (tid < 128) ((u64*)zbuf)[tid] = 0x8080808080808080ULL;
    for (int i = tid; i < 24576; i += 256) {
      int e = i & 15, colA = (i >> 4) & 15, q = (i >> 8) & 3, t = i >> 10;
      int mf = t % 12, ch = t / 12;
      signed char v = 0;
      if (e < 15 && (ch == 0 || q == 0)) {
        int ky = (ch == 0) ? q : 4;
        int ci = e / 5, kx = e - ci * 5;
        v = (signed char)(int)rintf(
            w0[((mf * 16 + colA) * 3 + ci) * 25 + ky * 5 + kx]);
      }
      w0q[i] = v;
    }
    for (int oc = tid; oc < 192; oc += 256) {
      const float* p = w0 + (size_t)oc * 75;
      int s = 0;
      #pragma unroll 5
      for (int j = 0; j < 75; j++) s += (int)rintf(p[j]);
      totw0[oc] = s;
    }
  }
}

// ---------------------------------------------------------------------------
// conv0F: fused layer-0 (unchanged).
// ---------------------------------------------------------------------------
__global__ __launch_bounds__(192, 3) void conv0F(
    const float* __restrict__ x, const signed char* __restrict__ wq,
    const float* __restrict__ bias, const float* __restrict__ mulv,
    const int* __restrict__ totw,
    const int* __restrict__ reluP, const int* __restrict__ mdP,
    unsigned char* __restrict__ outA)
{
  __shared__ signed char ilds[3][5][132];

  const int tid = threadIdx.x;
  const int lane = tid & 63;
  const int col = lane & 15;
  const int quad = lane >> 4;
  const int w = tid >> 6;
  const int blk = blockIdx.x;
  const int oxblk = blk & 3;
  const int oy = (blk >> 2) & 255;
  const int b = blk >> 10;
  const int oxbase = oxblk * 64;

  i32x4 afr[2][4];
  #pragma unroll
  for (int ch = 0; ch < 2; ch++)
    #pragma unroll
    for (int i = 0; i < 4; i++)
      afr[ch][i] = *(const i32x4*)(wq + ch * 12288 + (w * 4 + i) * 1024 + lane * 16);

  const float* xb = x + (size_t)b * 3 * 512 * 512;
  for (int i = tid; i < 990; i += 192) {
    int j = i % 66; int t = i / 66; int r = t % 5; int ci = t / 5;
    int iy = 2 * oy - 2 + r;
    int ix = 2 * oxbase - 2 + 2 * j;
    int v0 = -128, v1 = -128;
    if ((unsigned)iy < 512u) {
      const float* row = xb + ((size_t)ci * 512 + iy) * 512;
      if ((unsigned)ix < 512u) {
        float xv = rintf(row[ix] * 256.0f);
        v0 = (int)fminf(fmaxf(xv, 0.0f), 255.0f) - 128;
      }
      if ((unsigned)(ix + 1) < 512u) {
        float xv = rintf(row[ix + 1] * 256.0f);
        v1 = (int)fminf(fmaxf(xv, 0.0f), 255.0f) - 128;
      }
    }
    *(unsigned short*)&ilds[ci][r][2 * j] =
        (unsigned short)((v0 & 0xFF) | ((v1 & 0xFF) << 8));
  }
  __syncthreads();

  i32x4 acc[4][4];
  #pragma unroll
  for (int fm = 0; fm < 4; fm++)
    #pragma unroll
    for (int fn = 0; fn < 4; fn++) acc[fm][fn] = (i32x4){0, 0, 0, 0};

  #pragma unroll
  for (int ch = 0; ch < 2; ch++) {
    const int row = (ch == 0) ? quad : 4;
    i32x4 bfr[4];
    #pragma unroll
    for (int fn = 0; fn < 4; fn++) {
      const int xb2 = 2 * (fn * 16 + col);
      const int o8 = (xb2 & 3) * 8;
      const int ab = xb2 & ~3;
      u64 w0_, w1_, w2_;
      {
        const u32* p0 = (const u32*)&ilds[0][row][ab];
        const u32* p1 = (const u32*)&ilds[1][row][ab];
        const u32* p2 = (const u32*)&ilds[2][row][ab];
        w0_ = (u64)p0[0] | ((u64)p0[1] << 32);
        w1_ = (u64)p1[0] | ((u64)p1[1] << 32);
        w2_ = (u64)p2[0] | ((u64)p2[1] << 32);
      }
      u32 a0 = (u32)(w0_ >> o8);
      u32 a1 = ((u32)(w0_ >> (o8 + 32)) & 0xFFu) | (((u32)(w1_ >> o8)) << 8);
      u32 a2 = ((u32)(w1_ >> (o8 + 24)) & 0xFFFFu) | (((u32)(w2_ >> o8)) << 16);
      u32 a3 = (u32)(w2_ >> (o8 + 16));
      bfr[fn] = (i32x4){(int)a0, (int)a1, (int)a2, (int)a3};
    }
    #pragma unroll
    for (int fm = 0; fm < 4; fm++)
      #pragma unroll
      for (int fn = 0; fn < 4; fn++)
        acc[fm][fn] = __builtin_amdgcn_mfma_i32_16x16x64_i8(
            afr[ch][fm], bfr[fn], acc[fm][fn], 0, 0, 0);
  }

  const size_t pix0 = ((size_t)(b * 256 + oy)) * 256 + oxbase;
  const int rl = reluP[0];
  const int sh = mdP[0];
  const ll clpv_ll = llrint(255.0 / (double)rl * 16777216.0);
  const int clpv = clpv_ll > 0x7FFFFFFFLL ? 0x7FFFFFFF : (int)clpv_ll;
  const int sclv = (int)((rl + 4) >> 3);
  const int rnd = 1 << (sh - 1);
  #pragma unroll
  for (int fm = 0; fm < 4; fm++) {
    const int oc0 = w * 64 + fm * 16 + quad * 4;
    int bim[4], mu32[4];
    #pragma unroll
    for (int r = 0; r < 4; r++) {
      int bi = (int)llrintf(bias[oc0 + r] * 256.0f) + 128 * totw[oc0 + r];
      mu32[r] = (int)llrintf(mulv[oc0 + r]);
      bim[r] = bi * mu32[r];
    }
    #pragma unroll
    for (int fn = 0; fn < 4; fn++) {
      const size_t pix = pix0 + fn * 16 + col;
      u32 wd = 0;
      #pragma unroll
      for (int r = 0; r < 4; r++) {
        int vi = acc[fm][fn][r] * mu32[r] + bim[r];
        int y = (vi + rnd) >> sh;
        y = y < 0 ? 0 : (y > clpv ? clpv : y);
        y = (y * sclv + (1 << 20)) >> 21;
        wd |= (((u32)y ^ 0x80u) & 0xFFu) << (8 * r);
      }
      *(u32*)(outA + pix * 192 + oc0) = wd;
    }
  }
}

// ---------------------------------------------------------------------------
// Layers 1-3: all-compute FIFO pipeline (R10 structure, verified) with
// PR-row tiles. Block = PR output rows x 16*NH cols; NB = PR*NH convoys /
// B-frags per K-unit. PR=2 doubles the grid (L1: 512 -> 1024 = 4 blocks/CU,
// 16 waves/CU) at constant per-SIMD MFMA work — 4-way latency hiding per
// SIMD instead of 2-way (R9-R11 plateau: both resident waves stalled ~38%
// of cycles). LDS ring 4 x NB KB = 16 KB.
// FIFO invariant (in-order vmcnt retirement, m135): comp(sl) waits own
// A(sl); every staging wave's stage(sl) is OLDER than its A(sl-1) waited at
// comp(sl-1) before the preceding barrier => all stage(sl) landed. WAR:
// stage(sl+3) overwrites slot (sl-1)&3 whose reads completed pre-barrier.
// ---------------------------------------------------------------------------
template <int COUT, int HIN, int WIN, int HOUT, int WOUT, int WV,
          int KSPLIT, bool DIRECT, int NH, int PR>
__global__ __launch_bounds__(WV * 64, 4) void convS(
    const signed char* __restrict__ act, const signed char* __restrict__ wp,
    const float* __restrict__ bias, const float* __restrict__ mulv,
    const int* __restrict__ totw,
    const int* __restrict__ reluP, const int* __restrict__ mdP,
    const signed char* __restrict__ zbuf,
    unsigned char* __restrict__ outA, int* __restrict__ outP)
{
  constexpr int CIN = 192;
  constexpr int MF = COUT / 16;
  constexpr int OCW = COUT / WV;          // oc per wave (48 or 64)
  constexpr int FM = OCW / 16;            // MFMA row-tiles per wave (3 or 4)
  constexpr int SAe = MF * 1024;          // A bytes per (tap,ch) unit
  constexpr int TX = WOUT / (16 * NH);
  constexpr int TYB = HOUT / PR;
  constexpr int TPP = 25 / KSPLIT;
  constexpr int NSTEP = TPP * 3;          // 75 or 15
  constexpr int NB = PR * NH;             // convoys / B-frags per unit
  constexpr int BUFB = NB * 1024;
  constexpr int SMAX = (NB + WV - 1) / WV;
  constexpr int PSZ = 4 * HOUT * WOUT * COUT;
  static_assert(WV * OCW == COUT, "M covers COUT");
  static_assert(NSTEP >= 4, "pipeline depth");

  __shared__ __align__(16) char smem[4 * BUFB];

  const int tid = threadIdx.x;
  const int lane = tid & 63;
  const int col = lane & 15;
  const int quad = lane >> 4;
  const int w = tid >> 6;
  const int part = blockIdx.y;

  int bx = blockIdx.x;
  const int tx = bx % TX; bx /= TX;
  const int ty = bx % TYB;
  const int b = bx / TYB;
  const int ox0 = tx * 16 * NH;
  const int oy0 = ty * PR;
  const int tap0 = part * TPP;

  // ---- staging share: convoys j = w + k*WV (k < SMAX, j < NB) ----
  const signed char* bp[SMAX];
  int mjx[SMAX], mjy[SMAX];
  #pragma unroll
  for (int k = 0; k < SMAX; k++) {
    const int j = w + k * WV;
    if (j < NB) {
      const int p = j / NH, h = j % NH;
      const int oxv = ox0 + h * 16 + col;
      const int oyv = oy0 + p;
      bp[k] = act + ((size_t)b * HIN * WIN + (size_t)(2 * oyv) * WIN + 2 * oxv) * CIN
              + quad * 16;
      int mx = 0, my = 0;
      #pragma unroll
      for (int kk = 0; kk < 5; kk++) {
        if ((unsigned)(2 * oxv + kk - 2) < (unsigned)WIN) mx |= 1 << kk;
        if ((unsigned)(2 * oyv + kk - 2) < (unsigned)HIN) my |= 1 << kk;
      }
      mjx[k] = mx; mjy[k] = my;
    }
  }
  int kyS = tap0 / 5, kxS = tap0 - 5 * kyS, chS = 0;
  auto stage = [&](int sel) {
    const int offB = ((kyS - 2) * WIN + (kxS - 2)) * CIN + chS * 64;
    #pragma unroll
    for (int k = 0; k < SMAX; k++) {
      const int j = w + k * WV;
      if (j < NB) {
        bool v = ((mjx[k] >> kxS) & 1) && ((mjy[k] >> kyS) & 1);
        const signed char* g = v ? (bp[k] + offB) : (zbuf + quad * 16);
        load_lds16(g, smem + sel * BUFB + j * 1024);
      }
    }
    chS++;
    if (chS == 3) { chS = 0; kxS++; if (kxS == 5) { kxS = 0; kyS++; } }
  };

  // ---- accumulators / A double-bank ----
  i32x4 acc[FM][NB];
  #pragma unroll
  for (int fm = 0; fm < FM; fm++)
    #pragma unroll
    for (int j = 0; j < NB; j++) acc[fm][j] = (i32x4){0, 0, 0, 0};

  const signed char* aptr = wp + (size_t)(tap0 * 3) * SAe + w * FM * 1024 + lane * 16;
  i32x4 aA[FM], aB[FM];
  #pragma unroll
  for (int i = 0; i < FM; i++) aA[i] = *(const i32x4*)(aptr + i * 1024);

  auto comp = [&](int base, i32x4 (&a)[FM]) {
    const char* pB = smem + base + lane * 16;
    i32x4 bfr[NB];
    #pragma unroll
    for (int i = 0; i < NB; i++)
      bfr[i] = *(const i32x4*)(pB + i * 1024);
    #pragma unroll
    for (int fm = 0; fm < FM; fm++)
      #pragma unroll
      for (int j = 0; j < NB; j++)
        acc[fm][j] = __builtin_amdgcn_mfma_i32_16x16x64_i8(
            a[fm], bfr[j], acc[fm][j], 0, 0, 0);
  };

  // ---- prologue: A(0); stages 0..2; wait own A(0)+stage(0) ----
  stage(0); stage(1); stage(2);
  asm volatile("s_waitcnt vmcnt(2)" ::: "memory");
  asm volatile("s_barrier" ::: "memory");

  int sl = 0;
  #pragma unroll 1
  for (; sl + 1 < NSTEP; sl += 2) {
    aptr += SAe;                            // A(sl+1) -> aB  (BEFORE stage)
    #pragma unroll
    for (int i = 0; i < FM; i++) aB[i] = *(const i32x4*)(aptr + i * 1024);
    if (sl + 3 < NSTEP) stage((sl + 3) & 3);
    comp((sl & 3) * BUFB, aA);              // auto vmcnt: A(sl) done => stage(sl+1) landed
    asm volatile("s_barrier" ::: "memory");
    if (sl + 2 < NSTEP) {
      aptr += SAe;                          // A(sl+2) -> aA
      #pragma unroll
      for (int i = 0; i < FM; i++) aA[i] = *(const i32x4*)(aptr + i * 1024);
    }
    if (sl + 4 < NSTEP) stage((sl + 4) & 3);
    comp(((sl + 1) & 3) * BUFB, aB);
    if (sl + 2 < NSTEP) asm volatile("s_barrier" ::: "memory");
  }
  if (sl < NSTEP) {                         // tail (NSTEP odd)
    comp((sl & 3) * BUFB, aA);
  }

  // ---- epilogue ----
  if constexpr (DIRECT) {
    const int rl = reluP[0];
    const int sh = mdP[0] - 8;
    const ll clpv = llrint(255.0 / (double)rl * 16777216.0);
    const ll sclv = (ll)((rl + 4) >> 3);
    #pragma unroll
    for (int fm = 0; fm < FM; fm++) {
      const int oc0 = w * OCW + fm * 16 + quad * 4;
      ll bi[4], mu[4];
      #pragma unroll
      for (int r = 0; r < 4; r++) {
        bi[r] = llrintf(bias[oc0 + r]) + 128LL * totw[oc0 + r];
        mu[r] = llrintf(mulv[oc0 + r]);
      }
      #pragma unroll
      for (int j = 0; j < NB; j++) {
        const int p = j / NH, h = j % NH;
        const int oyv = oy0 + p;
        const int oxv = ox0 + h * 16 + col;
        u32 wd = 0;
        #pragma unroll
        for (int r = 0; r < 4; r++) {
          ll vi = ((ll)acc[fm][j][r] + bi[r]) * mu[r];
          ll y = (vi + (1LL << (sh - 1))) >> sh;
          y = y < 0 ? 0LL : (y > clpv ? clpv : y);
          y = (y * sclv + (1LL << 20)) >> 21;
          wd |= (((u32)y ^ 0x80u) & 0xFFu) << (8 * r);
        }
        *(u32*)(outA + ((size_t)((b * HOUT + oyv) * WOUT + oxv)) * COUT + oc0) = wd;
      }
    }
  } else {
    int* pout = outP + (size_t)part * PSZ;
    #pragma unroll
    for (int fm = 0; fm < FM; fm++) {
      const int oc0 = w * OCW + fm * 16 + quad * 4;
      #pragma unroll
      for (int j = 0; j < NB; j++) {
        const int p = j / NH, h = j % NH;
        const int oyv = oy0 + p;
        const int oxv = ox0 + h * 16 + col;
        *(i32x4*)(pout + ((size_t)((b * HOUT + oyv) * WOUT + oxv)) * COUT + oc0) =
            acc[fm][j];
      }
    }
  }
}

// ---------------------------------------------------------------------------
// reduce2: sum 5 L2 partials + integer epilogue -> act3 (i8, channels-last).
// ---------------------------------------------------------------------------
__global__ __launch_bounds__(256) void reduce2(
    const int* __restrict__ partP, const float* __restrict__ bias,
    const float* __restrict__ mulv, const int* __restrict__ totw,
    const int* __restrict__ reluP, const int* __restrict__ mdP,
    unsigned char* __restrict__ outA)
{
  const int gid = blockIdx.x * 256 + threadIdx.x;   // 786432
  const int PSZ4 = 4 * 64 * 64 * 192 / 4;
  const int4* pp = (const int4*)partP;
  int4 sv = pp[gid];
  #pragma unroll
  for (int p = 1; p < 5; p++) {
    int4 v = pp[(size_t)p * PSZ4 + gid];
    sv.x += v.x; sv.y += v.y; sv.z += v.z; sv.w += v.w;
  }
  int sa[4] = {sv.x, sv.y, sv.z, sv.w};
  const int oc0 = (gid * 4) % 192;
  const int rl = reluP[0];
  const int sh = mdP[0] - 8;
  const ll clpv = llrint(255.0 / (double)rl * 16777216.0);
  const ll sclv = (ll)((rl + 4) >> 3);
  u32 wd = 0;
  #pragma unroll
  for (int r = 0; r < 4; r++) {
    ll bi = llrintf(bias[oc0 + r]) + 128LL * totw[oc0 + r];
    ll mu = llrintf(mulv[oc0 + r]);
    ll vi = ((ll)sa[r] + bi) * mu;
    ll y = (vi + (1LL << (sh - 1))) >> sh;
    y = y < 0 ? 0LL : (y > clpv ? clpv : y);
    y = (y * sclv + (1LL << 20)) >> 21;
    wd |= (((u32)y ^ 0x80u) & 0xFFu) << (8 * r);
  }
  ((u32*)outA)[gid] = wd;
}

// ---------------------------------------------------------------------------
// reduce3: sum 5 L3 partials + final shift -> d_out f32 NCHW (coalesced write).
// ---------------------------------------------------------------------------
__global__ __launch_bounds__(256) void reduce3(
    const int* __restrict__ partP, const float* __restrict__ b3,
    const float* __restrict__ mul3, const int* __restrict__ totw3,
    const int* __restrict__ mdP, const int* __restrict__ gaP,
    float* __restrict__ outF)
{
  const int gid = blockIdx.x * 256 + threadIdx.x;   // 1310720
  int t = gid;
  const int ox = t & 31; t >>= 5;
  const int oy = t & 31; t >>= 5;
  const int oc = t % 320;
  const int b  = t / 320;
  const int PSZ = 4 * 32 * 32 * 320;
  const size_t src = ((size_t)((b * 32 + oy) * 32 + ox)) * 320 + oc;
  ll s = 0;
  #pragma unroll
  for (int p = 0; p < 5; p++) s += partP[(size_t)p * PSZ + src];
  const int sh = mdP[0] - gaP[0];
  const ll bi = llrintf(b3[oc]) + 128LL * totw3[oc];
  const ll mu = llrintf(mul3[oc]);
  const ll y = ((s + bi) * mu + (1LL << (sh - 1))) >> sh;
  outF[gid] = (float)y;
}

// ---------------------------------------------------------------------------
extern "C" void kernel_launch(void* const* d_in, const int* in_sizes, int n_in,
                              void* d_out, int out_size, void* d_ws, size_t ws_size,
                              hipStream_t stream)
{
  const float* x    = (const float*)d_in[0];
  const float* w0   = (const float*)d_in[1];
  const float* b0   = (const float*)d_in[2];
  const float* w1   = (const float*)d_in[3];
  const float* b1   = (const float*)d_in[4];
  const float* w2   = (const float*)d_in[5];
  const float* b2   = (const float*)d_in[6];
  const float* w3   = (const float*)d_in[7];
  const float* b3   = (const float*)d_in[8];
  const float* mul0 = (const float*)d_in[9];
  const float* mul1 = (const float*)d_in[10];
  const float* mul2 = (const float*)d_in[11];
  const float* mul3 = (const float*)d_in[12];
  const int* relu0  = (const int*)d_in[13];
  const int* relu1  = (const int*)d_in[14];
  const int* relu2  = (const int*)d_in[15];
  const int* md0    = (const int*)d_in[16];
  const int* md1    = (const int*)d_in[17];
  const int* md2    = (const int*)d_in[18];
  const int* md3    = (const int*)d_in[19];
  const int* ga     = (const int*)d_in[20];

  char* ws = (char*)d_ws;
  size_t off = 0;
  signed char* zbuf = (signed char*)(ws + off); off += 1024;
  signed char* w0q  = (signed char*)(ws + off); off += 24576;
  signed char* w1p  = (signed char*)(ws + off); off += 921600;
  signed char* w2p  = (signed char*)(ws + off); off += 921600;
  signed char* w3p  = (signed char*)(ws + off); off += 1536000;
  int*         totw1= (int*)        (ws + off); off += 192 * 4;
  int*         totw2= (int*)        (ws + off); off += 192 * 4;
  int*         totw3= (int*)        (ws + off); off += 320 * 4;
  int*         totw0= (int*)        (ws + off); off += 192 * 4;
  unsigned char* act1 = (unsigned char*)(ws + off); off += (size_t)4 * 256 * 256 * 192;
  unsigned char* act2 = (unsigned char*)(ws + off); off += (size_t)4 * 128 * 128 * 192;
  unsigned char* act3 = (unsigned char*)(ws + off); off += (size_t)4 * 64 * 64 * 192;
  int*         partl  = (int*)(ws + off); off += (size_t)5 * 4 * 64 * 64 * 192 * 4; // 62.9MB
  (void)ws_size; (void)in_sizes; (void)n_in; (void)out_size;

  hipMemsetAsync(totw1, 0, (192 + 192 + 320 + 192) * 4, stream);
  // weight packing (LDS transpose) + weight sums
  prep_all<<<89, 256, 0, stream>>>(w0, w1, w2, w3, w0q, w1p, w2p, w3p,
                                   zbuf, totw0, totw1, totw2, totw3);
  // L0 fused: quantize + in-register im2col + GEMM (M=192, N=262144, K=128)
  conv0F<<<4096, 192, 0, stream>>>(x, w0q, b0, mul0, totw0, relu0, md0, act1);
  // L1: 256x256 -> 128x128x192 ; 1024 blocks (4/CU, 16 waves/CU) ; 2x32 tile
  convS<192, 256, 256, 128, 128, 4, 1, true, 2, 2><<<dim3(1024, 1), 256, 0, stream>>>(
      (const signed char*)act1, w1p, b1, mul1, totw1, relu1, md1, zbuf, act2, nullptr);
  // L2: 128x128 -> 64x64x192 ; split-K 5 ; 2x32 tile ; i32 partials
  convS<192, 128, 128, 64, 64, 4, 5, false, 2, 2><<<dim3(256, 5), 256, 0, stream>>>(
      (const signed char*)act2, w2p, b2, mul2, totw2, relu2, md2, zbuf, nullptr, partl);
  reduce2<<<3072, 256, 0, stream>>>(partl, b2, mul2, totw2, relu2, md2, act3);
  // L3: 64x64 -> 32x32x320 ; split-K 5 ; 5 waves ; 2x16 tile ; i32 partials
  convS<320, 64, 64, 32, 32, 5, 5, false, 1, 2><<<dim3(128, 5), 320, 0, stream>>>(
      (const signed char*)act3, w3p, b3, mul3, totw3, nullptr, md3, zbuf, nullptr, partl);
  reduce3<<<5120, 256, 0, stream>>>(partl, b3, mul3, totw3, md3, ga, (float*)d_out);
}

// Round 13
// 316.013 us; speedup vs baseline: 1.0878x; 1.0704x over previous
//
#include <hip/hip_runtime.h>
#include <hip/hip_bf16.h>

typedef int i32x4 __attribute__((ext_vector_type(4)));
typedef unsigned int u32;
typedef unsigned long long u64;
typedef long long ll;

// async 16B global->LDS copy. LDS dest = wave-uniform base + lane*16.
__device__ __forceinline__ void load_lds16(const void* g, void* l) {
  __builtin_amdgcn_global_load_lds(
      (const __attribute__((address_space(1))) u32*)g,
      (__attribute__((address_space(3))) u32*)l, 16, 0, 0);
}

// ---------------------------------------------------------------------------
// prep_all: weight packing via LDS transpose (coalesced reads) + totw sums.
// (unchanged)
// ---------------------------------------------------------------------------
__global__ __launch_bounds__(256) void prep_all(
    const float* __restrict__ w0, const float* __restrict__ w1,
    const float* __restrict__ w2, const float* __restrict__ w3,
    signed char* __restrict__ w0q, signed char* __restrict__ w1p,
    signed char* __restrict__ w2p, signed char* __restrict__ w3p,
    signed char* __restrict__ zbuf,
    int* __restrict__ totw0, int* __restrict__ totw1,
    int* __restrict__ totw2, int* __restrict__ totw3)
{
  __shared__ signed char ldsw[8 * 4800];   // 38400 B
  const int blk = blockIdx.x;
  const int tid = threadIdx.x;

  if (blk < 88) {
    const float* wsrc; signed char* wdst; int* tot; int MF, sub;
    if (blk < 24)      { wsrc = w1; wdst = w1p; tot = totw1; MF = 12; sub = blk; }
    else if (blk < 48) { wsrc = w2; wdst = w2p; tot = totw2; MF = 12; sub = blk - 24; }
    else               { wsrc = w3; wdst = w3p; tot = totw3; MF = 20; sub = blk - 48; }
    const int mf = sub >> 1, half = sub & 1, colbase = half * 8;
    const int ocb = mf * 16 + colbase;
    // ---- phase A: coalesced read + quantize + per-oc sums ----
    for (int o = 0; o < 8; o++) {
      const float* src = wsrc + (size_t)(ocb + o) * 4800;
      int s = 0;
      for (int j = tid; j < 4800; j += 256) {
        int v = (int)rintf(src[j]);
        ldsw[o * 4800 + j] = (signed char)v;
        s += v;
      }
      atomicAdd(&tot[ocb + o], s);
    }
    __syncthreads();
    // ---- phase B: packed u32 writes (coalesced) ----
    for (int u = tid; u < 9600; u += 256) {
      int eu = u & 3, colL = (u >> 2) & 7, q = (u >> 5) & 3, t = u >> 7;
      int tap = t / 3, ch = t - 3 * tap;
      int ci0 = ch * 64 + q * 16 + eu * 4;
      const signed char* sp = ldsw + colL * 4800 + tap;
      u32 wv = 0;
      #pragma unroll
      for (int bb = 0; bb < 4; bb++)
        wv |= ((u32)(unsigned char)sp[(ci0 + bb) * 25]) << (8 * bb);
      *(u32*)(wdst + ((size_t)t * MF + mf) * 1024 +
              (q * 16 + colbase + colL) * 16 + eu * 4) = wv;
    }
  } else {
    // ---- blk 88: zbuf + w0q custom pack + w0 sums ----
    if (tid < 128) ((u64*)zbuf)[tid] = 0x8080808080808080ULL;
    for (int i = tid; i < 24576; i += 256) {
      int e = i & 15, colA = (i >> 4) & 15, q = (i >> 8) & 3, t = i >> 10;
      int mf = t % 12, ch = t / 12;
      signed char v = 0;
      if (e < 15 && (ch == 0 || q == 0)) {
        int ky = (ch == 0) ? q : 4;
        int ci = e / 5, kx = e - ci * 5;
        v = (signed char)(int)rintf(
            w0[((mf * 16 + colA) * 3 + ci) * 25 + ky * 5 + kx]);
      }
      w0q[i] = v;
    }
    for (int oc = tid; oc < 192; oc += 256) {
      const float* p = w0 + (size_t)oc * 75;
      int s = 0;
      #pragma unroll 5
      for (int j = 0; j < 75; j++) s += (int)rintf(p[j]);
      totw0[oc] = s;
    }
  }
}

// ---------------------------------------------------------------------------
// conv0F: fused layer-0. Staging now uses float2 loads (adjacent pixel pair;
// ix is always even so one bounds check covers both lanes of the pair).
// ---------------------------------------------------------------------------
__global__ __launch_bounds__(192, 3) void conv0F(
    const float* __restrict__ x, const signed char* __restrict__ wq,
    const float* __restrict__ bias, const float* __restrict__ mulv,
    const int* __restrict__ totw,
    const int* __restrict__ reluP, const int* __restrict__ mdP,
    unsigned char* __restrict__ outA)
{
  __shared__ signed char ilds[3][5][132];

  const int tid = threadIdx.x;
  const int lane = tid & 63;
  const int col = lane & 15;
  const int quad = lane >> 4;
  const int w = tid >> 6;
  const int blk = blockIdx.x;
  const int oxblk = blk & 3;
  const int oy = (blk >> 2) & 255;
  const int b = blk >> 10;
  const int oxbase = oxblk * 64;

  i32x4 afr[2][4];
  #pragma unroll
  for (int ch = 0; ch < 2; ch++)
    #pragma unroll
    for (int i = 0; i < 4; i++)
      afr[ch][i] = *(const i32x4*)(wq + ch * 12288 + (w * 4 + i) * 1024 + lane * 16);

  const float* xb = x + (size_t)b * 3 * 512 * 512;
  for (int i = tid; i < 990; i += 192) {
    int j = i % 66; int t = i / 66; int r = t % 5; int ci = t / 5;
    int iy = 2 * oy - 2 + r;
    int ix = 2 * oxbase - 2 + 2 * j;     // even
    int v0 = -128, v1 = -128;
    if ((unsigned)iy < 512u && (unsigned)ix < 512u) {
      // ix even & in [0,510] => ix+1 also valid; single check suffices.
      const float2 xv = *(const float2*)(xb + ((size_t)ci * 512 + iy) * 512 + ix);
      float a0 = rintf(xv.x * 256.0f);
      float a1 = rintf(xv.y * 256.0f);
      v0 = (int)fminf(fmaxf(a0, 0.0f), 255.0f) - 128;
      v1 = (int)fminf(fmaxf(a1, 0.0f), 255.0f) - 128;
    }
    *(unsigned short*)&ilds[ci][r][2 * j] =
        (unsigned short)((v0 & 0xFF) | ((v1 & 0xFF) << 8));
  }
  __syncthreads();

  i32x4 acc[4][4];
  #pragma unroll
  for (int fm = 0; fm < 4; fm++)
    #pragma unroll
    for (int fn = 0; fn < 4; fn++) acc[fm][fn] = (i32x4){0, 0, 0, 0};

  #pragma unroll
  for (int ch = 0; ch < 2; ch++) {
    const int row = (ch == 0) ? quad : 4;
    i32x4 bfr[4];
    #pragma unroll
    for (int fn = 0; fn < 4; fn++) {
      const int xb2 = 2 * (fn * 16 + col);
      const int o8 = (xb2 & 3) * 8;
      const int ab = xb2 & ~3;
      u64 w0_, w1_, w2_;
      {
        const u32* p0 = (const u32*)&ilds[0][row][ab];
        const u32* p1 = (const u32*)&ilds[1][row][ab];
        const u32* p2 = (const u32*)&ilds[2][row][ab];
        w0_ = (u64)p0[0] | ((u64)p0[1] << 32);
        w1_ = (u64)p1[0] | ((u64)p1[1] << 32);
        w2_ = (u64)p2[0] | ((u64)p2[1] << 32);
      }
      u32 a0 = (u32)(w0_ >> o8);
      u32 a1 = ((u32)(w0_ >> (o8 + 32)) & 0xFFu) | (((u32)(w1_ >> o8)) << 8);
      u32 a2 = ((u32)(w1_ >> (o8 + 24)) & 0xFFFFu) | (((u32)(w2_ >> o8)) << 16);
      u32 a3 = (u32)(w2_ >> (o8 + 16));
      bfr[fn] = (i32x4){(int)a0, (int)a1, (int)a2, (int)a3};
    }
    #pragma unroll
    for (int fm = 0; fm < 4; fm++)
      #pragma unroll
      for (int fn = 0; fn < 4; fn++)
        acc[fm][fn] = __builtin_amdgcn_mfma_i32_16x16x64_i8(
            afr[ch][fm], bfr[fn], acc[fm][fn], 0, 0, 0);
  }

  const size_t pix0 = ((size_t)(b * 256 + oy)) * 256 + oxbase;
  const int rl = reluP[0];
  const int sh = mdP[0];
  const ll clpv_ll = llrint(255.0 / (double)rl * 16777216.0);
  const int clpv = clpv_ll > 0x7FFFFFFFLL ? 0x7FFFFFFF : (int)clpv_ll;
  const int sclv = (int)((rl + 4) >> 3);
  const int rnd = 1 << (sh - 1);
  #pragma unroll
  for (int fm = 0; fm < 4; fm++) {
    const int oc0 = w * 64 + fm * 16 + quad * 4;
    int bim[4], mu32[4];
    #pragma unroll
    for (int r = 0; r < 4; r++) {
      int bi = (int)llrintf(bias[oc0 + r] * 256.0f) + 128 * totw[oc0 + r];
      mu32[r] = (int)llrintf(mulv[oc0 + r]);
      bim[r] = bi * mu32[r];
    }
    #pragma unroll
    for (int fn = 0; fn < 4; fn++) {
      const size_t pix = pix0 + fn * 16 + col;
      u32 wd = 0;
      #pragma unroll
      for (int r = 0; r < 4; r++) {
        int vi = acc[fm][fn][r] * mu32[r] + bim[r];
        int y = (vi + rnd) >> sh;
        y = y < 0 ? 0 : (y > clpv ? clpv : y);
        y = (y * sclv + (1 << 20)) >> 21;
        wd |= (((u32)y ^ 0x80u) & 0xFFu) << (8 * r);
      }
      *(u32*)(outA + pix * 192 + oc0) = wd;
    }
  }
}

// ---------------------------------------------------------------------------
// Layers 1-3: all-compute FIFO pipeline (R10 structure, verified) with
// selectable K-split axis. CHS=false: split by taps (NPART parts, TPP taps
// each). CHS=true: split by CHANNEL-GROUP (NPART=3 parts; part = ch-group;
// each part runs all 25 taps for its 64 channels; NSTEP=25; A-stride 3*SAe).
// Channel split cuts split-K partial traffic 5/3x (fewer parts) at identical
// act-stage volume and identical per-step shape (NB convoys, FM*NB MFMA).
// FIFO invariant unchanged (in-order vmcnt retirement, m135): comp(sl)
// auto-waits own A(sl), issued after stage(sl) => stage landed; no drain.
// ---------------------------------------------------------------------------
template <int COUT, int HIN, int WIN, int HOUT, int WOUT, int WV,
          int NPART, bool CHS, bool DIRECT, int NH>
__global__ __launch_bounds__(WV * 64, 2) void convS(
    const signed char* __restrict__ act, const signed char* __restrict__ wp,
    const float* __restrict__ bias, const float* __restrict__ mulv,
    const int* __restrict__ totw,
    const int* __restrict__ reluP, const int* __restrict__ mdP,
    const signed char* __restrict__ zbuf,
    unsigned char* __restrict__ outA, int* __restrict__ outP)
{
  constexpr int CIN = 192;
  constexpr int PASSES = 4;
  constexpr int MF = COUT / 16;
  constexpr int OCW = COUT / WV;          // oc per wave (48 or 64)
  constexpr int FM = OCW / 16;            // MFMA row-tiles per wave (3 or 4)
  constexpr int SAe = MF * 1024;          // A bytes per (tap,ch) unit
  constexpr int ASTRIDE = CHS ? 3 * SAe : SAe;
  constexpr int TX = WOUT / (16 * NH);
  constexpr int TYB = HOUT / 4;
  constexpr int TPP = CHS ? 25 : 25 / NPART;
  constexpr int NSTEP = CHS ? 25 : TPP * 3;   // 75 / 25 / 15
  constexpr int NB = PASSES * NH;         // convoys / B-frags per unit
  constexpr int BUFB = NB * 1024;
  constexpr int SMAX = (NB + WV - 1) / WV;
  constexpr int PSZ = 4 * HOUT * WOUT * COUT;
  static_assert(WV * OCW == COUT, "M covers COUT");
  static_assert(NSTEP >= 4, "pipeline depth");

  __shared__ __align__(16) char smem[4 * BUFB];

  const int tid = threadIdx.x;
  const int lane = tid & 63;
  const int col = lane & 15;
  const int quad = lane >> 4;
  const int w = tid >> 6;
  const int part = blockIdx.y;

  int bx = blockIdx.x;
  const int tx = bx % TX; bx /= TX;
  const int ty = bx % TYB;
  const int b = bx / TYB;
  const int ox0 = tx * 16 * NH;
  const int oy0 = ty * 4;
  const int tap0 = CHS ? 0 : part * TPP;

  // ---- staging share: convoys j = w + k*WV (k < SMAX, j < NB) ----
  const signed char* bp[SMAX];
  int mjx[SMAX], mjy[SMAX];
  #pragma unroll
  for (int k = 0; k < SMAX; k++) {
    const int j = w + k * WV;
    if (j < NB) {
      const int p = j / NH, h = j % NH;
      const int oxv = ox0 + h * 16 + col;
      const int oyv = oy0 + p;
      bp[k] = act + ((size_t)b * HIN * WIN + (size_t)(2 * oyv) * WIN + 2 * oxv) * CIN
              + quad * 16;
      int mx = 0, my = 0;
      #pragma unroll
      for (int kk = 0; kk < 5; kk++) {
        if ((unsigned)(2 * oxv + kk - 2) < (unsigned)WIN) mx |= 1 << kk;
        if ((unsigned)(2 * oyv + kk - 2) < (unsigned)HIN) my |= 1 << kk;
      }
      mjx[k] = mx; mjy[k] = my;
    }
  }
  int kyS = tap0 / 5, kxS = tap0 - 5 * kyS;
  int chS = CHS ? part : 0;
  auto stage = [&](int sel) {
    const int offB = ((kyS - 2) * WIN + (kxS - 2)) * CIN + chS * 64;
    #pragma unroll
    for (int k = 0; k < SMAX; k++) {
      const int j = w + k * WV;
      if (j < NB) {
        bool v = ((mjx[k] >> kxS) & 1) && ((mjy[k] >> kyS) & 1);
        const signed char* g = v ? (bp[k] + offB) : (zbuf + quad * 16);
        load_lds16(g, smem + sel * BUFB + j * 1024);
      }
    }
    if constexpr (CHS) {
      kxS++; if (kxS == 5) { kxS = 0; kyS++; }
    } else {
      chS++;
      if (chS == 3) { chS = 0; kxS++; if (kxS == 5) { kxS = 0; kyS++; } }
    }
  };

  // ---- accumulators / A double-bank ----
  i32x4 acc[FM][NB];
  #pragma unroll
  for (int fm = 0; fm < FM; fm++)
    #pragma unroll
    for (int j = 0; j < NB; j++) acc[fm][j] = (i32x4){0, 0, 0, 0};

  const signed char* aptr = wp + (size_t)(CHS ? part : tap0 * 3) * SAe
                            + w * FM * 1024 + lane * 16;
  i32x4 aA[FM], aB[FM];
  #pragma unroll
  for (int i = 0; i < FM; i++) aA[i] = *(const i32x4*)(aptr + i * 1024);

  auto comp = [&](int base, i32x4 (&a)[FM]) {
    const char* pB = smem + base + lane * 16;
    i32x4 bfr[NB];
    #pragma unroll
    for (int i = 0; i < NB; i++)
      bfr[i] = *(const i32x4*)(pB + i * 1024);
    #pragma unroll
    for (int fm = 0; fm < FM; fm++)
      #pragma unroll
      for (int j = 0; j < NB; j++)
        acc[fm][j] = __builtin_amdgcn_mfma_i32_16x16x64_i8(
            a[fm], bfr[j], acc[fm][j], 0, 0, 0);
  };

  // ---- prologue: A(0); stages 0..2; wait own A(0)+stage(0) ----
  stage(0); stage(1); stage(2);
  if constexpr (SMAX == 2) asm volatile("s_waitcnt vmcnt(4)" ::: "memory");
  else                     asm volatile("s_waitcnt vmcnt(2)" ::: "memory");
  asm volatile("s_barrier" ::: "memory");

  int sl = 0;
  #pragma unroll 1
  for (; sl + 1 < NSTEP; sl += 2) {
    aptr += ASTRIDE;                        // A(sl+1) -> aB  (BEFORE stage)
    #pragma unroll
    for (int i = 0; i < FM; i++) aB[i] = *(const i32x4*)(aptr + i * 1024);
    if (sl + 3 < NSTEP) stage((sl + 3) & 3);
    comp((sl & 3) * BUFB, aA);              // auto vmcnt: A(sl) done => stage(sl+1) landed
    asm volatile("s_barrier" ::: "memory");
    if (sl + 2 < NSTEP) {
      aptr += ASTRIDE;                      // A(sl+2) -> aA
      #pragma unroll
      for (int i = 0; i < FM; i++) aA[i] = *(const i32x4*)(aptr + i * 1024);
    }
    if (sl + 4 < NSTEP) stage((sl + 4) & 3);
    comp(((sl + 1) & 3) * BUFB, aB);
    if (sl + 2 < NSTEP) asm volatile("s_barrier" ::: "memory");
  }
  if (sl < NSTEP) {                         // tail (NSTEP odd)
    comp((sl & 3) * BUFB, aA);
  }

  // ---- epilogue ----
  if constexpr (DIRECT) {
    const int rl = reluP[0];
    const int sh = mdP[0] - 8;
    const ll clpv = llrint(255.0 / (double)rl * 16777216.0);
    const ll sclv = (ll)((rl + 4) >> 3);
    #pragma unroll
    for (int fm = 0; fm < FM; fm++) {
      const int oc0 = w * OCW + fm * 16 + quad * 4;
      ll bi[4], mu[4];
      #pragma unroll
      for (int r = 0; r < 4; r++) {
        bi[r] = llrintf(bias[oc0 + r]) + 128LL * totw[oc0 + r];
        mu[r] = llrintf(mulv[oc0 + r]);
      }
      #pragma unroll
      for (int j = 0; j < NB; j++) {
        const int p = j / NH, h = j % NH;
        const int oyv = oy0 + p;
        const int oxv = ox0 + h * 16 + col;
        u32 wd = 0;
        #pragma unroll
        for (int r = 0; r < 4; r++) {
          ll vi = ((ll)acc[fm][j][r] + bi[r]) * mu[r];
          ll y = (vi + (1LL << (sh - 1))) >> sh;
          y = y < 0 ? 0LL : (y > clpv ? clpv : y);
          y = (y * sclv + (1LL << 20)) >> 21;
          wd |= (((u32)y ^ 0x80u) & 0xFFu) << (8 * r);
        }
        *(u32*)(outA + ((size_t)((b * HOUT + oyv) * WOUT + oxv)) * COUT + oc0) = wd;
      }
    }
  } else {
    int* pout = outP + (size_t)part * PSZ;
    #pragma unroll
    for (int fm = 0; fm < FM; fm++) {
      const int oc0 = w * OCW + fm * 16 + quad * 4;
      #pragma unroll
      for (int j = 0; j < NB; j++) {
        const int p = j / NH, h = j % NH;
        const int oyv = oy0 + p;
        const int oxv = ox0 + h * 16 + col;
        *(i32x4*)(pout + ((size_t)((b * HOUT + oyv) * WOUT + oxv)) * COUT + oc0) =
            acc[fm][j];
      }
    }
  }
}

// ---------------------------------------------------------------------------
// reduce2: sum 3 L2 channel-split partials + integer epilogue -> act3 (i8).
// ---------------------------------------------------------------------------
__global__ __launch_bounds__(256) void reduce2(
    const int* __restrict__ partP, const float* __restrict__ bias,
    const float* __restrict__ mulv, const int* __restrict__ totw,
    const int* __restrict__ reluP, const int* __restrict__ mdP,
    unsigned char* __restrict__ outA)
{
  const int gid = blockIdx.x * 256 + threadIdx.x;   // 786432
  const int PSZ4 = 4 * 64 * 64 * 192 / 4;
  const int4* pp = (const int4*)partP;
  int4 sv = pp[gid];
  #pragma unroll
  for (int p = 1; p < 3; p++) {
    int4 v = pp[(size_t)p * PSZ4 + gid];
    sv.x += v.x; sv.y += v.y; sv.z += v.z; sv.w += v.w;
  }
  int sa[4] = {sv.x, sv.y, sv.z, sv.w};
  const int oc0 = (gid * 4) % 192;
  const int rl = reluP[0];
  const int sh = mdP[0] - 8;
  const ll clpv = llrint(255.0 / (double)rl * 16777216.0);
  const ll sclv = (ll)((rl + 4) >> 3);
  u32 wd = 0;
  #pragma unroll
  for (int r = 0; r < 4; r++) {
    ll bi = llrintf(bias[oc0 + r]) + 128LL * totw[oc0 + r];
    ll mu = llrintf(mulv[oc0 + r]);
    ll vi = ((ll)sa[r] + bi) * mu;
    ll y = (vi + (1LL << (sh - 1))) >> sh;
    y = y < 0 ? 0LL : (y > clpv ? clpv : y);
    y = (y * sclv + (1LL << 20)) >> 21;
    wd |= (((u32)y ^ 0x80u) & 0xFFu) << (8 * r);
  }
  ((u32*)outA)[gid] = wd;
}

// ---------------------------------------------------------------------------
// reduce3: sum 3 L3 channel-split partials + final shift -> d_out f32 NCHW.
// ---------------------------------------------------------------------------
__global__ __launch_bounds__(256) void reduce3(
    const int* __restrict__ partP, const float* __restrict__ b3,
    const float* __restrict__ mul3, const int* __restrict__ totw3,
    const int* __restrict__ mdP, const int* __restrict__ gaP,
    float* __restrict__ outF)
{
  const int gid = blockIdx.x * 256 + threadIdx.x;   // 1310720
  int t = gid;
  const int ox = t & 31; t >>= 5;
  const int oy = t & 31; t >>= 5;
  const int oc = t % 320;
  const int b  = t / 320;
  const int PSZ = 4 * 32 * 32 * 320;
  const size_t src = ((size_t)((b * 32 + oy) * 32 + ox)) * 320 + oc;
  ll s = 0;
  #pragma unroll
  for (int p = 0; p < 3; p++) s += partP[(size_t)p * PSZ + src];
  const int sh = mdP[0] - gaP[0];
  const ll bi = llrintf(b3[oc]) + 128LL * totw3[oc];
  const ll mu = llrintf(mul3[oc]);
  const ll y = ((s + bi) * mu + (1LL << (sh - 1))) >> sh;
  outF[gid] = (float)y;
}

// ---------------------------------------------------------------------------
extern "C" void kernel_launch(void* const* d_in, const int* in_sizes, int n_in,
                              void* d_out, int out_size, void* d_ws, size_t ws_size,
                              hipStream_t stream)
{
  const float* x    = (const float*)d_in[0];
  const float* w0   = (const float*)d_in[1];
  const float* b0   = (const float*)d_in[2];
  const float* w1   = (const float*)d_in[3];
  const float* b1   = (const float*)d_in[4];
  const float* w2   = (const float*)d_in[5];
  const float* b2   = (const float*)d_in[6];
  const float* w3   = (const float*)d_in[7];
  const float* b3   = (const float*)d_in[8];
  const float* mul0 = (const float*)d_in[9];
  const float* mul1 = (const float*)d_in[10];
  const float* mul2 = (const float*)d_in[11];
  const float* mul3 = (const float*)d_in[12];
  const int* relu0  = (const int*)d_in[13];
  const int* relu1  = (const int*)d_in[14];
  const int* relu2  = (const int*)d_in[15];
  const int* md0    = (const int*)d_in[16];
  const int* md1    = (const int*)d_in[17];
  const int* md2    = (const int*)d_in[18];
  const int* md3    = (const int*)d_in[19];
  const int* ga     = (const int*)d_in[20];

  char* ws = (char*)d_ws;
  size_t off = 0;
  signed char* zbuf = (signed char*)(ws + off); off += 1024;
  signed char* w0q  = (signed char*)(ws + off); off += 24576;
  signed char* w1p  = (signed char*)(ws + off); off += 921600;
  signed char* w2p  = (signed char*)(ws + off); off += 921600;
  signed char* w3p  = (signed char*)(ws + off); off += 1536000;
  int*         totw1= (int*)        (ws + off); off += 192 * 4;
  int*         totw2= (int*)        (ws + off); off += 192 * 4;
  int*         totw3= (int*)        (ws + off); off += 320 * 4;
  int*         totw0= (int*)        (ws + off); off += 192 * 4;
  unsigned char* act1 = (unsigned char*)(ws + off); off += (size_t)4 * 256 * 256 * 192;
  unsigned char* act2 = (unsigned char*)(ws + off); off += (size_t)4 * 128 * 128 * 192;
  unsigned char* act3 = (unsigned char*)(ws + off); off += (size_t)4 * 64 * 64 * 192;
  int*         partl  = (int*)(ws + off); off += (size_t)5 * 4 * 64 * 64 * 192 * 4; // 62.9MB
  (void)ws_size; (void)in_sizes; (void)n_in; (void)out_size;

  hipMemsetAsync(totw1, 0, (192 + 192 + 320 + 192) * 4, stream);
  // weight packing (LDS transpose) + weight sums
  prep_all<<<89, 256, 0, stream>>>(w0, w1, w2, w3, w0q, w1p, w2p, w3p,
                                   zbuf, totw0, totw1, totw2, totw3);
  // L0 fused: quantize + in-register im2col + GEMM (M=192, N=262144, K=128)
  conv0F<<<4096, 192, 0, stream>>>(x, w0q, b0, mul0, totw0, relu0, md0, act1);
  // L1: 256x256 -> 128x128x192 ; 512 blocks x 4 waves ; N=128 ; full-K
  convS<192, 256, 256, 128, 128, 4, 1, false, true, 2><<<dim3(512, 1), 256, 0, stream>>>(
      (const signed char*)act1, w1p, b1, mul1, totw1, relu1, md1, zbuf, act2, nullptr);
  // L2: 128x128 -> 64x64x192 ; CHANNEL-split 3 ; N=128 ; i32 partials
  convS<192, 128, 128, 64, 64, 4, 3, true, false, 2><<<dim3(128, 3), 256, 0, stream>>>(
      (const signed char*)act2, w2p, b2, mul2, totw2, relu2, md2, zbuf, nullptr, partl);
  reduce2<<<3072, 256, 0, stream>>>(partl, b2, mul2, totw2, relu2, md2, act3);
  // L3: 64x64 -> 32x32x320 ; CHANNEL-split 3 ; 5 waves ; N=64 ; i32 partials
  convS<320, 64, 64, 32, 32, 5, 3, true, false, 1><<<dim3(64, 3), 320, 0, stream>>>(
      (const signed char*)act3, w3p, b3, mul3, totw3, nullptr, md3, zbuf, nullptr, partl);
  reduce3<<<5120, 256, 0, stream>>>(partl, b3, mul3, totw3, md3, ga, (float*)d_out);
}